// Round 1
// baseline (2580.895 us; speedup 1.0000x reference)
//
#include <hip/hip_runtime.h>

#define NN 200000
#define NE 400000
#define DD 128
#define NL 5
#define AV 100
#define BV 10
#define EPSV 1e-5f

// h[n][d] = sum_c atom_tables[c][x[n][c]][d]; also initializes total (d_out)
__global__ __launch_bounds__(256) void k_encode(const int* __restrict__ x,
    const float* __restrict__ at, float* __restrict__ hbuf, float* __restrict__ out) {
  int idx = blockIdx.x * 256 + threadIdx.x;       // N*D threads, exact
  int n = idx >> 7, d = idx & 127;
  const int* xr = x + n * 9;
  float s = 0.f;
#pragma unroll
  for (int c = 0; c < 9; ++c)
    s += at[(c * AV + xr[c]) * DD + d];
  hbuf[idx] = s;
  out[idx] = s;
}

__global__ __launch_bounds__(256) void k_deg_init(float* __restrict__ deg) {
  int i = blockIdx.x * 256 + threadIdx.x;
  if (i < NN) deg[i] = 1.0f;
}

__global__ __launch_bounds__(256) void k_deg_count(const int* __restrict__ ei,
                                                   float* __restrict__ deg) {
  int e = blockIdx.x * 256 + threadIdx.x;
  if (e < NE) atomicAdd(&deg[ei[e]], 1.0f);       // row = source
}

__global__ __launch_bounds__(256) void k_deg_fin(const float* __restrict__ deg,
    float* __restrict__ dis, float* __restrict__ invd) {
  int i = blockIdx.x * 256 + threadIdx.x;
  if (i < NN) {
    float dg = deg[i];
    dis[i] = rsqrtf(dg);
    invd[i] = 1.0f / dg;
  }
}

__global__ __launch_bounds__(256) void k_norm(const int* __restrict__ ei,
    const float* __restrict__ dis, float* __restrict__ nrm) {
  int e = blockIdx.x * 256 + threadIdx.x;
  if (e < NE) nrm[e] = dis[ei[e]] * dis[ei[NE + e]];
}

// hl = h @ Wl^T + bl.  Block: 64 nodes x 128 cols, 256 threads, 4x8 reg tile.
__global__ __launch_bounds__(256) void k_gemm(const float* __restrict__ h,
    const float* __restrict__ Wl, const float* __restrict__ bl,
    float* __restrict__ hl) {
  // wlds[k][dout] = Wl[dout][k] (transposed); padded rows keep float4 align (132*4=528B, 16B-mult)
  __shared__ __align__(16) float wlds[32][DD + 4];
  __shared__ __align__(16) float hlds[32][64 + 4];   // hlds[k][n], 68*4=272B rows
  int t = threadIdx.x;
  int c = t & 15;        // col group: cols c*8 .. c*8+7
  int r = t >> 4;        // row group: nodes r*4 .. r*4+3
  int n0 = blockIdx.x * 64;

  float acc[4][8];
#pragma unroll
  for (int i = 0; i < 4; ++i)
#pragma unroll
    for (int j = 0; j < 8; ++j) acc[i][j] = 0.f;

  for (int kt = 0; kt < DD; kt += 32) {
#pragma unroll
    for (int i = 0; i < 16; ++i) {                 // stage W tile: 32x128
      int idx = i * 256 + t;
      int kk = idx & 31, dout = idx >> 5;
      wlds[kk][dout] = Wl[dout * DD + kt + kk];
    }
#pragma unroll
    for (int i = 0; i < 8; ++i) {                  // stage h tile: 32x64 (transposed)
      int idx = i * 256 + t;
      int kk = idx & 31, n = idx >> 5;
      hlds[kk][n] = h[(n0 + n) * DD + kt + kk];
    }
    __syncthreads();
#pragma unroll
    for (int kk = 0; kk < 32; ++kk) {
      float4 hv = *(const float4*)&hlds[kk][r * 4];
      float4 w0 = *(const float4*)&wlds[kk][c * 8];
      float4 w1 = *(const float4*)&wlds[kk][c * 8 + 4];
      float hvv[4] = {hv.x, hv.y, hv.z, hv.w};
      float wv[8] = {w0.x, w0.y, w0.z, w0.w, w1.x, w1.y, w1.z, w1.w};
#pragma unroll
      for (int i = 0; i < 4; ++i)
#pragma unroll
        for (int j = 0; j < 8; ++j) acc[i][j] += hvv[i] * wv[j];
    }
    __syncthreads();
  }

  float bb[8];
#pragma unroll
  for (int j = 0; j < 8; ++j) bb[j] = bl[c * 8 + j];
#pragma unroll
  for (int i = 0; i < 4; ++i) {
    int n = n0 + r * 4 + i;
    float4 o0, o1;
    o0.x = acc[i][0] + bb[0]; o0.y = acc[i][1] + bb[1];
    o0.z = acc[i][2] + bb[2]; o0.w = acc[i][3] + bb[3];
    o1.x = acc[i][4] + bb[4]; o1.y = acc[i][5] + bb[5];
    o1.z = acc[i][6] + bb[6]; o1.w = acc[i][7] + bb[7];
    *(float4*)&hl[n * DD + c * 8] = o0;
    *(float4*)&hl[n * DD + c * 8 + 4] = o1;
  }
}

// msg = norm * relu(hl[row] + edge_emb), scatter-add to agg[col]. Bond emb fused.
__global__ __launch_bounds__(256) void k_scatter(const float* __restrict__ hl,
    const int* __restrict__ ei, const int* __restrict__ ea,
    const float* __restrict__ bt, const float* __restrict__ nrm,
    float* __restrict__ agg) {
  int idx = blockIdx.x * 256 + threadIdx.x;       // E*D threads, exact
  int e = idx >> 7, d = idx & 127;
  int rs = ei[e], ct = ei[NE + e];
  float ee = bt[(0 * BV + ea[e * 3 + 0]) * DD + d]
           + bt[(1 * BV + ea[e * 3 + 1]) * DD + d]
           + bt[(2 * BV + ea[e * 3 + 2]) * DD + d];
  float v = fmaxf(hl[rs * DD + d] + ee, 0.f) * nrm[e];
  atomicAdd(&agg[ct * DD + d], v);
}

// pre = agg + relu(hl + root)/deg (in-place into agg) + per-column sum/sumsq partials
__global__ __launch_bounds__(256) void k_combine(float* __restrict__ agg,
    const float* __restrict__ hl, const float* __restrict__ rootl,
    const float* __restrict__ invd, float* __restrict__ gsum,
    float* __restrict__ gss) {
  __shared__ float s1[256], s2[256];
  int t = threadIdx.x, d = t & 127, half = t >> 7;
  int n0 = blockIdx.x * 160;                      // 1250 blocks * 160 rows = N exact
  float rt = rootl[d];
  float s = 0.f, ss = 0.f;
  for (int n = n0 + half; n < n0 + 160; n += 2) {
    int ix = n * DD + d;
    float pre = agg[ix] + fmaxf(hl[ix] + rt, 0.f) * invd[n];
    agg[ix] = pre;
    s += pre;
    ss += pre * pre;
  }
  s1[t] = s; s2[t] = ss;
  __syncthreads();
  if (t < 128) {
    atomicAdd(&gsum[d], s1[t] + s1[t + 128]);
    atomicAdd(&gss[d],  s2[t] + s2[t + 128]);
  }
}

__global__ void k_bnfin(const float* __restrict__ gsum, const float* __restrict__ gss,
    const float* __restrict__ gl, const float* __restrict__ bl,
    float* __restrict__ scale, float* __restrict__ shift) {
  int d = threadIdx.x;
  float m = gsum[d] * (1.0f / NN);
  float v = gss[d] * (1.0f / NN) - m * m;
  float sc = gl[d] * rsqrtf(v + EPSV);
  scale[d] = sc;
  shift[d] = bl[d] - m * sc;
}

// out_bn = pre*scale + shift (+relu); total += out_bn; hbuf = out_bn; agg zeroed for next layer
__global__ __launch_bounds__(256) void k_apply(float* __restrict__ pre,
    const float* __restrict__ scale, const float* __restrict__ shift,
    float* __restrict__ hbuf, float* __restrict__ out, int do_relu) {
  int idx = blockIdx.x * 256 + threadIdx.x;       // N*D threads, exact
  int d = idx & 127;
  float v = pre[idx] * scale[d] + shift[d];
  pre[idx] = 0.f;                                 // re-zero agg for next layer's scatter
  if (do_relu) v = fmaxf(v, 0.f);
  hbuf[idx] = v;
  out[idx] += v;
}

extern "C" void kernel_launch(void* const* d_in, const int* in_sizes, int n_in,
                              void* d_out, int out_size, void* d_ws, size_t ws_size,
                              hipStream_t stream) {
  const int*   x     = (const int*)d_in[0];
  const int*   ei    = (const int*)d_in[1];   // [2, E]
  const int*   ea    = (const int*)d_in[2];   // [E, 3]
  const float* at    = (const float*)d_in[3];
  const float* bt    = (const float*)d_in[4];
  const float* W     = (const float*)d_in[5];
  const float* b     = (const float*)d_in[6];
  const float* root  = (const float*)d_in[7];
  const float* gamma = (const float*)d_in[8];
  const float* beta  = (const float*)d_in[9];
  float* out = (float*)d_out;

  float* ws = (float*)d_ws;
  size_t ND = (size_t)NN * DD;
  float* hbuf  = ws;            // N*D
  float* hl    = hbuf + ND;     // N*D
  float* agg   = hl + ND;       // N*D
  float* deg   = agg + ND;      // N
  float* dis   = deg + NN;      // N
  float* invd  = dis + NN;      // N
  float* nrm   = invd + NN;     // E
  float* gsum  = nrm + NE;      // D
  float* gss   = gsum + DD;     // D
  float* scale = gss + DD;      // D
  float* shift = scale + DD;    // D

  hipMemsetAsync(agg, 0, ND * sizeof(float), stream);
  k_encode<<<(int)(ND / 256), 256, 0, stream>>>(x, at, hbuf, out);
  k_deg_init<<<(NN + 255) / 256, 256, 0, stream>>>(deg);
  k_deg_count<<<(NE + 255) / 256, 256, 0, stream>>>(ei, deg);
  k_deg_fin<<<(NN + 255) / 256, 256, 0, stream>>>(deg, dis, invd);
  k_norm<<<(NE + 255) / 256, 256, 0, stream>>>(ei, dis, nrm);

  for (int l = 0; l < NL; ++l) {
    hipMemsetAsync(gsum, 0, 2 * DD * sizeof(float), stream);  // gsum+gss contiguous
    k_gemm<<<NN / 64, 256, 0, stream>>>(hbuf, W + (size_t)l * DD * DD, b + l * DD, hl);
    k_scatter<<<(int)((size_t)NE * DD / 256), 256, 0, stream>>>(hl, ei, ea, bt, nrm, agg);
    k_combine<<<NN / 160, 256, 0, stream>>>(agg, hl, root + l * DD, invd, gsum, gss);
    k_bnfin<<<1, DD, 0, stream>>>(gsum, gss, gamma + l * DD, beta + l * DD, scale, shift);
    k_apply<<<(int)(ND / 256), 256, 0, stream>>>(agg, scale, shift, hbuf, out,
                                                 (l < NL - 1) ? 1 : 0);
  }
}

// Round 2
// 2501.614 us; speedup vs baseline: 1.0317x; 1.0317x over previous
//
#include <hip/hip_runtime.h>

#define NN 200000
#define NE 400000
#define DD 128
#define NL 5
#define AV 100
#define BV 10
#define EPSV 1e-5f
#define SCAN_BLKS 196   // ceil(NN/1024)

// ---------- encode: h[n][d] = sum_c atom_tables[c][x[n][c]][d]; out = h ----------
__global__ __launch_bounds__(256) void k_encode(const int* __restrict__ x,
    const float* __restrict__ at, float* __restrict__ hbuf, float* __restrict__ out) {
  int idx = blockIdx.x * 256 + threadIdx.x;       // N*D threads, exact
  int n = idx >> 7, d = idx & 127;
  const int* xr = x + n * 9;
  float s = 0.f;
#pragma unroll
  for (int c = 0; c < 9; ++c)
    s += at[(c * AV + xr[c]) * DD + d];
  hbuf[idx] = s;
  out[idx] = s;
}

// ---------- degree ----------
__global__ __launch_bounds__(256) void k_deg_init(float* __restrict__ deg,
                                                  int* __restrict__ cnt) {
  int i = blockIdx.x * 256 + threadIdx.x;
  if (i < NN) { deg[i] = 1.0f; cnt[i] = 0; }
}

__global__ __launch_bounds__(256) void k_deg_count(const int* __restrict__ ei,
    float* __restrict__ deg, int* __restrict__ cnt) {
  int e = blockIdx.x * 256 + threadIdx.x;
  if (e < NE) {
    atomicAdd(&deg[ei[e]], 1.0f);        // out-degree of source (row)
    atomicAdd(&cnt[ei[NE + e]], 1);      // in-degree histogram by target (col)
  }
}

__global__ __launch_bounds__(256) void k_deg_fin(const float* __restrict__ deg,
    float* __restrict__ dis, float* __restrict__ invd) {
  int i = blockIdx.x * 256 + threadIdx.x;
  if (i < NN) {
    float dg = deg[i];
    dis[i] = rsqrtf(dg);
    invd[i] = 1.0f / dg;
  }
}

// ---------- exclusive scan of cnt -> off (3-kernel hierarchical) ----------
__global__ __launch_bounds__(256) void k_scan1(const int* __restrict__ cnt,
    int* __restrict__ off, int* __restrict__ bsum) {
  __shared__ int s[256];
  int t = threadIdx.x;
  int base = blockIdx.x * 1024 + t * 4;
  int c0 = (base + 0 < NN) ? cnt[base + 0] : 0;
  int c1 = (base + 1 < NN) ? cnt[base + 1] : 0;
  int c2 = (base + 2 < NN) ? cnt[base + 2] : 0;
  int c3 = (base + 3 < NN) ? cnt[base + 3] : 0;
  int tsum = c0 + c1 + c2 + c3;
  s[t] = tsum;
  __syncthreads();
  for (int o = 1; o < 256; o <<= 1) {
    int v = (t >= o) ? s[t - o] : 0;
    __syncthreads();
    s[t] += v;
    __syncthreads();
  }
  int excl = s[t] - tsum;
  if (base + 0 < NN) off[base + 0] = excl;
  if (base + 1 < NN) off[base + 1] = excl + c0;
  if (base + 2 < NN) off[base + 2] = excl + c0 + c1;
  if (base + 3 < NN) off[base + 3] = excl + c0 + c1 + c2;
  if (t == 255) bsum[blockIdx.x] = s[255];
}

__global__ __launch_bounds__(256) void k_scan2(const int* __restrict__ bsum,
    int* __restrict__ bbase) {
  __shared__ int s[256];
  int t = threadIdx.x;
  int v0 = (t < SCAN_BLKS) ? bsum[t] : 0;
  s[t] = v0;
  __syncthreads();
  for (int o = 1; o < 256; o <<= 1) {
    int v = (t >= o) ? s[t - o] : 0;
    __syncthreads();
    s[t] += v;
    __syncthreads();
  }
  if (t < SCAN_BLKS) bbase[t] = s[t] - v0;
}

__global__ __launch_bounds__(256) void k_scan3(int* __restrict__ off,
    const int* __restrict__ bbase, int* __restrict__ nxt) {
  int i = blockIdx.x * 256 + threadIdx.x;
  if (i < NN) {
    int v = off[i] + bbase[i >> 10];
    off[i] = v;
    nxt[i] = v;
  }
  if (i == 0) off[NN] = NE;
}

// ---------- fill CSR records: {row, packed_ea, norm_bits, 0} ----------
__global__ __launch_bounds__(256) void k_fill(const int* __restrict__ ei,
    const int* __restrict__ ea, const float* __restrict__ dis,
    int* __restrict__ nxt, int4* __restrict__ recs) {
  int e = blockIdx.x * 256 + threadIdx.x;
  if (e >= NE) return;
  int r = ei[e], c = ei[NE + e];
  int pa = ea[e * 3 + 0] + ea[e * 3 + 1] * 10 + ea[e * 3 + 2] * 100;
  float nr = dis[r] * dis[c];
  int pos = atomicAdd(&nxt[c], 1);
  recs[pos] = make_int4(r, pa, __float_as_int(nr), 0);
}

// ---------- combined bond table: btc[pa][d] ----------
__global__ __launch_bounds__(256) void k_btc(const float* __restrict__ bt,
    float* __restrict__ btc) {
  int idx = blockIdx.x * 256 + threadIdx.x;       // 1000*128 exact
  int p = idx >> 7, d = idx & 127;
  int a = p % 10, b = (p / 10) % 10, c = p / 100;
  btc[idx] = bt[(0 * BV + a) * DD + d] + bt[(1 * BV + b) * DD + d]
           + bt[(2 * BV + c) * DD + d];
}

// ---------- GEMM: hl = src' @ Wl^T + bl.  mode1: src'=relu(pre*scale+shift), out+= ----------
__global__ __launch_bounds__(256) void k_gemm(const float* __restrict__ src,
    const float* __restrict__ Wl, const float* __restrict__ bl,
    float* __restrict__ hl, const float* __restrict__ scale,
    const float* __restrict__ shift, float* __restrict__ outacc, int mode) {
  __shared__ __align__(16) float wlds[32][DD + 4];
  __shared__ __align__(16) float hlds[32][64 + 4];
  int t = threadIdx.x;
  int c = t & 15;
  int r = t >> 4;
  int n0 = blockIdx.x * 64;

  float acc[4][8];
#pragma unroll
  for (int i = 0; i < 4; ++i)
#pragma unroll
    for (int j = 0; j < 8; ++j) acc[i][j] = 0.f;

  for (int kt = 0; kt < DD; kt += 32) {
#pragma unroll
    for (int i = 0; i < 16; ++i) {
      int idx = i * 256 + t;
      int kk = idx & 31, dout = idx >> 5;
      wlds[kk][dout] = Wl[dout * DD + kt + kk];
    }
#pragma unroll
    for (int i = 0; i < 8; ++i) {
      int idx = i * 256 + t;
      int kk = idx & 31, n = idx >> 5;
      int gix = (n0 + n) * DD + kt + kk;
      float v;
      if (mode) {
        float p = src[gix];
        v = fmaxf(p * scale[kt + kk] + shift[kt + kk], 0.f);
        outacc[gix] += v;                // each (n,k) staged exactly once grid-wide
      } else {
        v = src[gix];
      }
      hlds[kk][n] = v;
    }
    __syncthreads();
#pragma unroll
    for (int kk = 0; kk < 32; ++kk) {
      float4 hv = *(const float4*)&hlds[kk][r * 4];
      float4 w0 = *(const float4*)&wlds[kk][c * 8];
      float4 w1 = *(const float4*)&wlds[kk][c * 8 + 4];
      float hvv[4] = {hv.x, hv.y, hv.z, hv.w};
      float wv[8] = {w0.x, w0.y, w0.z, w0.w, w1.x, w1.y, w1.z, w1.w};
#pragma unroll
      for (int i = 0; i < 4; ++i)
#pragma unroll
        for (int j = 0; j < 8; ++j) acc[i][j] += hvv[i] * wv[j];
    }
    __syncthreads();
  }

  float bb[8];
#pragma unroll
  for (int j = 0; j < 8; ++j) bb[j] = bl[c * 8 + j];
#pragma unroll
  for (int i = 0; i < 4; ++i) {
    int n = n0 + r * 4 + i;
    float4 o0, o1;
    o0.x = acc[i][0] + bb[0]; o0.y = acc[i][1] + bb[1];
    o0.z = acc[i][2] + bb[2]; o0.w = acc[i][3] + bb[3];
    o1.x = acc[i][4] + bb[4]; o1.y = acc[i][5] + bb[5];
    o1.z = acc[i][6] + bb[6]; o1.w = acc[i][7] + bb[7];
    *(float4*)&hl[n * DD + c * 8] = o0;
    *(float4*)&hl[n * DD + c * 8 + 4] = o1;
  }
}

// ---------- gather-aggregate + self term + BN partials (replaces scatter+combine) ----------
__global__ __launch_bounds__(256) void k_aggregate(const float* __restrict__ hl,
    const int* __restrict__ off, const int4* __restrict__ recs,
    const float* __restrict__ btc, const float* __restrict__ rootl,
    const float* __restrict__ invd, float* __restrict__ pre,
    float* __restrict__ gsum, float* __restrict__ gss) {
  __shared__ float s1[256], s2[256];
  int t = threadIdx.x, d = t & 127, nh = t >> 7;
  int n0 = blockIdx.x * 160;                      // 1250 blocks * 160 = N exact
  float rt = rootl[d];
  float s = 0.f, ss = 0.f;
  for (int n = n0 + nh; n < n0 + 160; n += 2) {
    int e0 = off[n], e1 = off[n + 1];
    float acc = 0.f;
    for (int e = e0; e < e1; ++e) {
      int4 rc = recs[e];                          // wave-uniform broadcast load
      float ee = btc[rc.y * DD + d];              // L2-resident 512KB table
      float hv = hl[rc.x * DD + d];               // coalesced 256B/wave gather
      acc += fmaxf(hv + ee, 0.f) * __int_as_float(rc.z);
    }
    float pv = acc + fmaxf(hl[n * DD + d] + rt, 0.f) * invd[n];
    pre[n * DD + d] = pv;
    s += pv;
    ss += pv * pv;
  }
  s1[t] = s; s2[t] = ss;
  __syncthreads();
  if (t < 128) {
    atomicAdd(&gsum[d], s1[t] + s1[t + 128]);
    atomicAdd(&gss[d],  s2[t] + s2[t + 128]);
  }
}

__global__ void k_bnfin(const float* __restrict__ gsum, const float* __restrict__ gss,
    const float* __restrict__ gl, const float* __restrict__ bl,
    float* __restrict__ scale, float* __restrict__ shift) {
  int d = threadIdx.x;
  float m = gsum[d] * (1.0f / NN);
  float v = gss[d] * (1.0f / NN) - m * m;
  float sc = gl[d] * rsqrtf(v + EPSV);
  scale[d] = sc;
  shift[d] = bl[d] - m * sc;
}

// ---------- final layer apply (no relu): out += pre*scale + shift ----------
__global__ __launch_bounds__(256) void k_apply_final(const float* __restrict__ pre,
    const float* __restrict__ scale, const float* __restrict__ shift,
    float* __restrict__ out) {
  int idx = blockIdx.x * 256 + threadIdx.x;       // N*D exact
  int d = idx & 127;
  out[idx] += pre[idx] * scale[d] + shift[d];
}

extern "C" void kernel_launch(void* const* d_in, const int* in_sizes, int n_in,
                              void* d_out, int out_size, void* d_ws, size_t ws_size,
                              hipStream_t stream) {
  const int*   x     = (const int*)d_in[0];
  const int*   ei    = (const int*)d_in[1];
  const int*   ea    = (const int*)d_in[2];
  const float* at    = (const float*)d_in[3];
  const float* bt    = (const float*)d_in[4];
  const float* W     = (const float*)d_in[5];
  const float* b     = (const float*)d_in[6];
  const float* root  = (const float*)d_in[7];
  const float* gamma = (const float*)d_in[8];
  const float* beta  = (const float*)d_in[9];
  float* out = (float*)d_out;

  float* ws = (float*)d_ws;
  size_t ND = (size_t)NN * DD;
  float* hbuf  = ws;                 // N*D
  float* hl    = hbuf + ND;          // N*D
  float* pre   = hl + ND;            // N*D
  float* deg   = pre + ND;           // N
  float* dis   = deg + NN;           // N
  float* invd  = dis + NN;           // N
  int*   cnt   = (int*)(invd + NN);  // N
  int*   offa  = cnt + NN;           // N+1 (+3 pad)
  int*   nxt   = offa + NN + 4;      // N
  int*   bsum  = nxt + NN;           // 256
  int*   bbase = bsum + 256;         // 256
  float* btc   = (float*)(bbase + 256);  // 1000*128
  float* gsum  = btc + 1000 * DD;    // D
  float* gss   = gsum + DD;          // D
  float* scaleb= gss + DD;           // D
  float* shiftb= scaleb + DD;        // D
  int4*  recs  = (int4*)(shiftb + DD);   // E*16B (offset is 16B-aligned: all chunks mult of 4 floats)

  // ---- precompute ----
  k_deg_init<<<(NN + 255) / 256, 256, 0, stream>>>(deg, cnt);
  k_deg_count<<<(NE + 255) / 256, 256, 0, stream>>>(ei, deg, cnt);
  k_deg_fin<<<(NN + 255) / 256, 256, 0, stream>>>(deg, dis, invd);
  k_scan1<<<SCAN_BLKS, 256, 0, stream>>>(cnt, offa, bsum);
  k_scan2<<<1, 256, 0, stream>>>(bsum, bbase);
  k_scan3<<<(NN + 255) / 256, 256, 0, stream>>>(offa, bbase, nxt);
  k_fill<<<(NE + 255) / 256, 256, 0, stream>>>(ei, ea, dis, nxt, recs);
  k_btc<<<1000 * DD / 256, 256, 0, stream>>>(bt, btc);
  k_encode<<<(int)(ND / 256), 256, 0, stream>>>(x, at, hbuf, out);

  // ---- layers ----
  for (int l = 0; l < NL; ++l) {
    hipMemsetAsync(gsum, 0, 2 * DD * sizeof(float), stream);
    if (l == 0)
      k_gemm<<<NN / 64, 256, 0, stream>>>(hbuf, W, b, hl, nullptr, nullptr, nullptr, 0);
    else
      k_gemm<<<NN / 64, 256, 0, stream>>>(pre, W + (size_t)l * DD * DD, b + l * DD,
                                          hl, scaleb, shiftb, out, 1);
    k_aggregate<<<NN / 160, 256, 0, stream>>>(hl, offa, recs, btc, root + l * DD,
                                              invd, pre, gsum, gss);
    k_bnfin<<<1, DD, 0, stream>>>(gsum, gss, gamma + l * DD, beta + l * DD,
                                  scaleb, shiftb);
  }
  k_apply_final<<<(int)(ND / 256), 256, 0, stream>>>(pre, scaleb, shiftb, out);
}

// Round 4
// 1665.628 us; speedup vs baseline: 1.5495x; 1.5019x over previous
//
#include <hip/hip_runtime.h>

#define NN 200000
#define NE 400000
#define DD 128
#define NL 5
#define AV 100
#define BV 10
#define EPSV 1e-5f
#define SCAN_BLKS 196   // ceil(NN/1024)

typedef short s8v __attribute__((ext_vector_type(8)));   // 8 bf16 (4 VGPRs)
typedef float f4v __attribute__((ext_vector_type(4)));   // 4 fp32 acc

__device__ __forceinline__ ushort f2bf(float f) {        // RNE float->bf16
  uint u = __float_as_uint(f);
  u += 0x7FFFu + ((u >> 16) & 1u);
  return (ushort)(u >> 16);
}

// ---------- encode: h = sum of atom embeddings; out(fp32) = h; hbuf(bf16) = h ----------
__global__ __launch_bounds__(256) void k_encode(const int* __restrict__ x,
    const float* __restrict__ at, ushort* __restrict__ hbuf, float* __restrict__ out) {
  int idx = blockIdx.x * 256 + threadIdx.x;       // N*D/2 threads exact
  int n = idx >> 6, dp = idx & 63;                // wave = one node -> x row broadcast
  const int* xr = x + n * 9;
  float s0 = 0.f, s1 = 0.f;
#pragma unroll
  for (int c = 0; c < 9; ++c) {
    float2 v = *(const float2*)&at[(c * AV + xr[c]) * DD + dp * 2];
    s0 += v.x; s1 += v.y;
  }
  *(float2*)&out[idx * 2] = make_float2(s0, s1);
  ((uint*)hbuf)[idx] = (uint)f2bf(s0) | ((uint)f2bf(s1) << 16);
}

// ---------- degree ----------
__global__ __launch_bounds__(256) void k_deg_init(float* __restrict__ deg,
                                                  int* __restrict__ cnt) {
  int i = blockIdx.x * 256 + threadIdx.x;
  if (i < NN) { deg[i] = 1.0f; cnt[i] = 0; }
}

__global__ __launch_bounds__(256) void k_deg_count(const int* __restrict__ ei,
    float* __restrict__ deg, int* __restrict__ cnt) {
  int e = blockIdx.x * 256 + threadIdx.x;
  if (e < NE) {
    atomicAdd(&deg[ei[e]], 1.0f);
    atomicAdd(&cnt[ei[NE + e]], 1);
  }
}

__global__ __launch_bounds__(256) void k_deg_fin(const float* __restrict__ deg,
    float* __restrict__ dis, float* __restrict__ invd) {
  int i = blockIdx.x * 256 + threadIdx.x;
  if (i < NN) {
    float dg = deg[i];
    dis[i] = rsqrtf(dg);
    invd[i] = 1.0f / dg;
  }
}

// ---------- exclusive scan of cnt -> off ----------
__global__ __launch_bounds__(256) void k_scan1(const int* __restrict__ cnt,
    int* __restrict__ off, int* __restrict__ bsum) {
  __shared__ int s[256];
  int t = threadIdx.x;
  int base = blockIdx.x * 1024 + t * 4;
  int c0 = (base + 0 < NN) ? cnt[base + 0] : 0;
  int c1 = (base + 1 < NN) ? cnt[base + 1] : 0;
  int c2 = (base + 2 < NN) ? cnt[base + 2] : 0;
  int c3 = (base + 3 < NN) ? cnt[base + 3] : 0;
  int tsum = c0 + c1 + c2 + c3;
  s[t] = tsum;
  __syncthreads();
  for (int o = 1; o < 256; o <<= 1) {
    int v = (t >= o) ? s[t - o] : 0;
    __syncthreads();
    s[t] += v;
    __syncthreads();
  }
  int excl = s[t] - tsum;
  if (base + 0 < NN) off[base + 0] = excl;
  if (base + 1 < NN) off[base + 1] = excl + c0;
  if (base + 2 < NN) off[base + 2] = excl + c0 + c1;
  if (base + 3 < NN) off[base + 3] = excl + c0 + c1 + c2;
  if (t == 255) bsum[blockIdx.x] = s[255];
}

__global__ __launch_bounds__(256) void k_scan2(const int* __restrict__ bsum,
    int* __restrict__ bbase) {
  __shared__ int s[256];
  int t = threadIdx.x;
  int v0 = (t < SCAN_BLKS) ? bsum[t] : 0;
  s[t] = v0;
  __syncthreads();
  for (int o = 1; o < 256; o <<= 1) {
    int v = (t >= o) ? s[t - o] : 0;
    __syncthreads();
    s[t] += v;
    __syncthreads();
  }
  if (t < SCAN_BLKS) bbase[t] = s[t] - v0;
}

__global__ __launch_bounds__(256) void k_scan3(int* __restrict__ off,
    const int* __restrict__ bbase, int* __restrict__ nxt) {
  int i = blockIdx.x * 256 + threadIdx.x;
  if (i < NN) {
    int v = off[i] + bbase[i >> 10];
    off[i] = v;
    nxt[i] = v;
  }
  if (i == 0) off[NN] = NE;
}

// ---------- fill CSR records: {row, packed_ea, norm_bits, 0} ----------
__global__ __launch_bounds__(256) void k_fill(const int* __restrict__ ei,
    const int* __restrict__ ea, const float* __restrict__ dis,
    int* __restrict__ nxt, int4* __restrict__ recs) {
  int e = blockIdx.x * 256 + threadIdx.x;
  if (e >= NE) return;
  int r = ei[e], c = ei[NE + e];
  int pa = ea[e * 3 + 0] + ea[e * 3 + 1] * 10 + ea[e * 3 + 2] * 100;
  float nr = dis[r] * dis[c];
  int pos = atomicAdd(&nxt[c], 1);
  recs[pos] = make_int4(r, pa, __float_as_int(nr), 0);
}

// ---------- combined bond table (fp32): btc[pa][d] ----------
__global__ __launch_bounds__(256) void k_btc(const float* __restrict__ bt,
    float* __restrict__ btc) {
  int idx = blockIdx.x * 256 + threadIdx.x;       // 1000*128 exact
  int p = idx >> 7, d = idx & 127;
  int a = p % 10, b = (p / 10) % 10, c = p / 100;
  btc[idx] = bt[(0 * BV + a) * DD + d] + bt[(1 * BV + b) * DD + d]
           + bt[(2 * BV + c) * DD + d];
}

// ---------- W -> bf16 ----------
__global__ __launch_bounds__(256) void k_wconv(const float* __restrict__ W,
    ushort* __restrict__ Wbf) {
  int i = blockIdx.x * 256 + threadIdx.x;         // 5*128*128 exact
  Wbf[i] = f2bf(W[i]);
}

// ---------- MFMA GEMM: hl(fp32) = A' @ Wl^T + bl ----------
// mode0: A' = hbuf (bf16).  mode1: A' = relu(pre*scale+shift) (fp32->bf16), fused out += A'.
// Per block: 128 nodes, 4 waves x 32 nodes. Fragments direct from global (no LDS).
__global__ __launch_bounds__(256) void k_gemm(const ushort* __restrict__ srcbf,
    const float* __restrict__ srcf, const ushort* __restrict__ Wbf,
    const float* __restrict__ bl, const float* __restrict__ scale,
    const float* __restrict__ shift, float* __restrict__ outacc,
    float* __restrict__ hl, int mode) {
  int t = threadIdx.x;
  int lane = t & 63, wave = t >> 6;
  int col = lane & 15, quad = lane >> 4;
  int nb = blockIdx.x * 128 + wave * 32;
  int r0 = nb + col, r1 = nb + 16 + col;
  bool v0 = r0 < NN, v1 = r1 < NN;
  long a0off = (long)(v0 ? r0 : NN - 1) * DD;
  long a1off = (long)(v1 ? r1 : NN - 1) * DD;

  f4v acc[2][8];
#pragma unroll
  for (int i = 0; i < 2; ++i)
#pragma unroll
    for (int j = 0; j < 8; ++j) acc[i][j] = (f4v)0.f;

#pragma unroll 1
  for (int ks = 0; ks < 4; ++ks) {
    int k0 = ks * 32 + quad * 8;                  // A[m=col][k=quad*8+j]
    s8v a0, a1;
    if (mode == 0) {
      a0 = *(const s8v*)&srcbf[a0off + k0];
      a1 = *(const s8v*)&srcbf[a1off + k0];
    } else {
      float4 sc0 = *(const float4*)&scale[k0];
      float4 sc1 = *(const float4*)&scale[k0 + 4];
      float4 sh0 = *(const float4*)&shift[k0];
      float4 sh1 = *(const float4*)&shift[k0 + 4];
      float scv[8] = {sc0.x, sc0.y, sc0.z, sc0.w, sc1.x, sc1.y, sc1.z, sc1.w};
      float shv[8] = {sh0.x, sh0.y, sh0.z, sh0.w, sh1.x, sh1.y, sh1.z, sh1.w};
      float4 p0 = *(const float4*)&srcf[a0off + k0];
      float4 p1 = *(const float4*)&srcf[a0off + k0 + 4];
      float w[8] = {p0.x, p0.y, p0.z, p0.w, p1.x, p1.y, p1.z, p1.w};
#pragma unroll
      for (int j = 0; j < 8; ++j) w[j] = fmaxf(w[j] * scv[j] + shv[j], 0.f);
      if (v0) {
        float4 o0 = *(const float4*)&outacc[a0off + k0];
        float4 o1 = *(const float4*)&outacc[a0off + k0 + 4];
        o0.x += w[0]; o0.y += w[1]; o0.z += w[2]; o0.w += w[3];
        o1.x += w[4]; o1.y += w[5]; o1.z += w[6]; o1.w += w[7];
        *(float4*)&outacc[a0off + k0] = o0;
        *(float4*)&outacc[a0off + k0 + 4] = o1;
      }
#pragma unroll
      for (int j = 0; j < 8; ++j) a0[j] = (short)f2bf(w[j]);
      p0 = *(const float4*)&srcf[a1off + k0];
      p1 = *(const float4*)&srcf[a1off + k0 + 4];
      float u[8] = {p0.x, p0.y, p0.z, p0.w, p1.x, p1.y, p1.z, p1.w};
#pragma unroll
      for (int j = 0; j < 8; ++j) u[j] = fmaxf(u[j] * scv[j] + shv[j], 0.f);
      if (v1) {
        float4 o0 = *(const float4*)&outacc[a1off + k0];
        float4 o1 = *(const float4*)&outacc[a1off + k0 + 4];
        o0.x += u[0]; o0.y += u[1]; o0.z += u[2]; o0.w += u[3];
        o1.x += u[4]; o1.y += u[5]; o1.z += u[6]; o1.w += u[7];
        *(float4*)&outacc[a1off + k0] = o0;
        *(float4*)&outacc[a1off + k0 + 4] = o1;
      }
#pragma unroll
      for (int j = 0; j < 8; ++j) a1[j] = (short)f2bf(u[j]);
    }
#pragma unroll
    for (int j = 0; j < 8; ++j) {                 // B[k][n=col] for out-tile j = W[j*16+col][k]
      s8v bf = *(const s8v*)&Wbf[(j * 16 + col) * DD + k0];
      acc[0][j] = __builtin_amdgcn_mfma_f32_16x16x32_bf16(a0, bf, acc[0][j], 0, 0, 0);
      acc[1][j] = __builtin_amdgcn_mfma_f32_16x16x32_bf16(a1, bf, acc[1][j], 0, 0, 0);
    }
  }

  float bb[8];
#pragma unroll
  for (int j = 0; j < 8; ++j) bb[j] = bl[j * 16 + col];
#pragma unroll
  for (int i = 0; i < 2; ++i) {
    int rowb = nb + i * 16 + quad * 4;            // D: col=lane&15, row=quad*4+reg
#pragma unroll
    for (int r = 0; r < 4; ++r) {
      int n = rowb + r;
      if (n < NN) {
#pragma unroll
        for (int j = 0; j < 8; ++j)
          hl[(long)n * DD + j * 16 + col] = acc[i][j][r] + bb[j];
      }
    }
  }
}

// ---------- gather-aggregate + self term + BN partials (fp32 hl/pre) ----------
__global__ __launch_bounds__(256) void k_aggregate(const float* __restrict__ hl,
    const int* __restrict__ off, const int4* __restrict__ recs,
    const float* __restrict__ btc, const float* __restrict__ rootl,
    const float* __restrict__ invd, float* __restrict__ pre,
    float* __restrict__ gsum, float* __restrict__ gss) {
  __shared__ float red[4][256];
  int t = threadIdx.x, dp = t & 63, slot = t >> 6; // wave == slot: uniform edge loop
  int n0 = blockIdx.x * 160;                       // 1250 blocks * 160 = N exact
  float rt0 = rootl[dp * 2], rt1 = rootl[dp * 2 + 1];
  float s0 = 0.f, s1 = 0.f, ss0 = 0.f, ss1 = 0.f;
  for (int n = n0 + slot; n < n0 + 160; n += 4) {
    int e0 = off[n], e1 = off[n + 1];
    float a0 = 0.f, a1 = 0.f;
    for (int e = e0; e < e1; ++e) {
      int4 rc = recs[e];                           // wave-uniform broadcast
      float2 hv = *(const float2*)&hl[(long)rc.x * DD + dp * 2];  // 512B/wave gather
      float2 ev = *(const float2*)&btc[rc.y * DD + dp * 2];       // L2-resident 512KB
      float nr = __int_as_float(rc.z);
      a0 += fmaxf(hv.x + ev.x, 0.f) * nr;
      a1 += fmaxf(hv.y + ev.y, 0.f) * nr;
    }
    float2 sv = *(const float2*)&hl[(long)n * DD + dp * 2];
    float iv = invd[n];
    float p0 = a0 + fmaxf(sv.x + rt0, 0.f) * iv;
    float p1 = a1 + fmaxf(sv.y + rt1, 0.f) * iv;
    *(float2*)&pre[(long)n * DD + dp * 2] = make_float2(p0, p1);
    s0 += p0; s1 += p1; ss0 += p0 * p0; ss1 += p1 * p1;
  }
  red[0][t] = s0; red[1][t] = s1; red[2][t] = ss0; red[3][t] = ss1;
  __syncthreads();
  if (t < 64) {
    float S0 = red[0][t] + red[0][t + 64] + red[0][t + 128] + red[0][t + 192];
    float S1 = red[1][t] + red[1][t + 64] + red[1][t + 128] + red[1][t + 192];
    float T0 = red[2][t] + red[2][t + 64] + red[2][t + 128] + red[2][t + 192];
    float T1 = red[3][t] + red[3][t + 64] + red[3][t + 128] + red[3][t + 192];
    atomicAdd(&gsum[2 * t], S0);
    atomicAdd(&gsum[2 * t + 1], S1);
    atomicAdd(&gss[2 * t], T0);
    atomicAdd(&gss[2 * t + 1], T1);
  }
}

__global__ void k_bnfin(const float* __restrict__ gsum, const float* __restrict__ gss,
    const float* __restrict__ gl, const float* __restrict__ bl,
    float* __restrict__ scale, float* __restrict__ shift) {
  int d = threadIdx.x;
  float m = gsum[d] * (1.0f / NN);
  float v = gss[d] * (1.0f / NN) - m * m;
  float sc = gl[d] * rsqrtf(v + EPSV);
  scale[d] = sc;
  shift[d] = bl[d] - m * sc;
}

// ---------- final layer apply (no relu): out += pre*scale + shift ----------
__global__ __launch_bounds__(256) void k_apply_final(const float* __restrict__ pre,
    const float* __restrict__ scale, const float* __restrict__ shift,
    float* __restrict__ out) {
  int idx = blockIdx.x * 256 + threadIdx.x;       // N*D/2 exact
  int dp = idx & 63;
  float2 pv = *(const float2*)&pre[idx * 2];
  float2 o = *(const float2*)&out[idx * 2];
  o.x += pv.x * scale[dp * 2] + shift[dp * 2];
  o.y += pv.y * scale[dp * 2 + 1] + shift[dp * 2 + 1];
  *(float2*)&out[idx * 2] = o;
}

extern "C" void kernel_launch(void* const* d_in, const int* in_sizes, int n_in,
                              void* d_out, int out_size, void* d_ws, size_t ws_size,
                              hipStream_t stream) {
  const int*   x     = (const int*)d_in[0];
  const int*   ei    = (const int*)d_in[1];
  const int*   ea    = (const int*)d_in[2];
  const float* at    = (const float*)d_in[3];
  const float* bt    = (const float*)d_in[4];
  const float* W     = (const float*)d_in[5];
  const float* b     = (const float*)d_in[6];
  const float* root  = (const float*)d_in[7];
  const float* gamma = (const float*)d_in[8];
  const float* beta  = (const float*)d_in[9];
  float* out = (float*)d_out;

  char* ws = (char*)d_ws;
  size_t ND = (size_t)NN * DD;
  float*  hl   = (float*)ws;                        // ND fp32
  float*  pre  = hl + ND;                           // ND fp32
  ushort* hbuf = (ushort*)(pre + ND);               // ND bf16
  int4*   recs = (int4*)(hbuf + ND);                // NE * 16B (offset mult of 16B)
  ushort* Wbf  = (ushort*)(recs + NE);              // 5*128*128 bf16
  float*  btc  = (float*)(Wbf + NL * DD * DD);      // 1000*128 fp32
  float*  deg  = btc + 1000 * DD;                   // N
  float*  dis  = deg + NN;                          // N
  float*  invd = dis + NN;                          // N
  int*    cnt  = (int*)(invd + NN);                 // N
  int*    offa = cnt + NN;                          // N+1 (+3 pad)
  int*    nxt  = offa + NN + 4;                     // N
  int*    bsum = nxt + NN;                          // 256
  int*    bbase= bsum + 256;                        // 256
  float*  gsum = (float*)(bbase + 256);             // D
  float*  gss  = gsum + DD;                         // D
  float*  scaleb = gss + DD;                        // D
  float*  shiftb = scaleb + DD;                     // D

  // ---- precompute ----
  k_deg_init<<<(NN + 255) / 256, 256, 0, stream>>>(deg, cnt);
  k_deg_count<<<(NE + 255) / 256, 256, 0, stream>>>(ei, deg, cnt);
  k_deg_fin<<<(NN + 255) / 256, 256, 0, stream>>>(deg, dis, invd);
  k_scan1<<<SCAN_BLKS, 256, 0, stream>>>(cnt, offa, bsum);
  k_scan2<<<1, 256, 0, stream>>>(bsum, bbase);
  k_scan3<<<(NN + 255) / 256, 256, 0, stream>>>(offa, bbase, nxt);
  k_fill<<<(NE + 255) / 256, 256, 0, stream>>>(ei, ea, dis, nxt, recs);
  k_btc<<<1000 * DD / 256, 256, 0, stream>>>(bt, btc);
  k_wconv<<<NL * DD * DD / 256, 256, 0, stream>>>(W, Wbf);
  k_encode<<<(int)(ND / 2 / 256), 256, 0, stream>>>(x, at, hbuf, out);

  // ---- layers ----
  for (int l = 0; l < NL; ++l) {
    hipMemsetAsync(gsum, 0, 2 * DD * sizeof(float), stream);
    k_gemm<<<(NN + 127) / 128, 256, 0, stream>>>(
        hbuf, pre, Wbf + (size_t)l * DD * DD, b + l * DD,
        scaleb, shiftb, out, hl, (l == 0) ? 0 : 1);
    k_aggregate<<<NN / 160, 256, 0, stream>>>(hl, offa, recs, btc, root + l * DD,
                                              invd, pre, gsum, gss);
    k_bnfin<<<1, DD, 0, stream>>>(gsum, gss, gamma + l * DD, beta + l * DD,
                                  scaleb, shiftb);
  }
  k_apply_final<<<(int)(ND / 2 / 256), 256, 0, stream>>>(pre, scaleb, shiftb, out);
}

// Round 5
// 1403.323 us; speedup vs baseline: 1.8391x; 1.1869x over previous
//
#include <hip/hip_runtime.h>

#define NN 200000
#define NE 400000
#define DD 128
#define NL 5
#define AV 100
#define BV 10
#define EPSV 1e-5f
#define SCAN_BLKS 196   // ceil(NN/1024)

typedef short s8v __attribute__((ext_vector_type(8)));   // 8 bf16 (4 VGPRs)
typedef float f4v __attribute__((ext_vector_type(4)));   // 4 fp32 acc

__device__ __forceinline__ ushort f2bf(float f) {        // RNE float->bf16
  uint u = __float_as_uint(f);
  u += 0x7FFFu + ((u >> 16) & 1u);
  return (ushort)(u >> 16);
}

// ---------- encode: h = sum of atom embeddings; out(fp32) = h; hbuf(bf16) = h ----------
__global__ __launch_bounds__(256) void k_encode(const int* __restrict__ x,
    const float* __restrict__ at, ushort* __restrict__ hbuf, float* __restrict__ out) {
  int idx = blockIdx.x * 256 + threadIdx.x;       // N*D/2 threads exact
  int n = idx >> 6, dp = idx & 63;                // wave = one node -> x row broadcast
  const int* xr = x + n * 9;
  float s0 = 0.f, s1 = 0.f;
#pragma unroll
  for (int c = 0; c < 9; ++c) {
    float2 v = *(const float2*)&at[(c * AV + xr[c]) * DD + dp * 2];
    s0 += v.x; s1 += v.y;
  }
  *(float2*)&out[idx * 2] = make_float2(s0, s1);
  ((uint*)hbuf)[idx] = (uint)f2bf(s0) | ((uint)f2bf(s1) << 16);
}

// ---------- degree ----------
__global__ __launch_bounds__(256) void k_deg_init(float* __restrict__ deg,
                                                  int* __restrict__ cnt) {
  int i = blockIdx.x * 256 + threadIdx.x;
  if (i < NN) { deg[i] = 1.0f; cnt[i] = 0; }
}

__global__ __launch_bounds__(256) void k_deg_count(const int* __restrict__ ei,
    float* __restrict__ deg, int* __restrict__ cnt) {
  int e = blockIdx.x * 256 + threadIdx.x;
  if (e < NE) {
    atomicAdd(&deg[ei[e]], 1.0f);
    atomicAdd(&cnt[ei[NE + e]], 1);
  }
}

__global__ __launch_bounds__(256) void k_deg_fin(const float* __restrict__ deg,
    float* __restrict__ dis, float* __restrict__ invd) {
  int i = blockIdx.x * 256 + threadIdx.x;
  if (i < NN) {
    float dg = deg[i];
    dis[i] = rsqrtf(dg);
    invd[i] = 1.0f / dg;
  }
}

// ---------- exclusive scan of cnt -> off ----------
__global__ __launch_bounds__(256) void k_scan1(const int* __restrict__ cnt,
    int* __restrict__ off, int* __restrict__ bsum) {
  __shared__ int s[256];
  int t = threadIdx.x;
  int base = blockIdx.x * 1024 + t * 4;
  int c0 = (base + 0 < NN) ? cnt[base + 0] : 0;
  int c1 = (base + 1 < NN) ? cnt[base + 1] : 0;
  int c2 = (base + 2 < NN) ? cnt[base + 2] : 0;
  int c3 = (base + 3 < NN) ? cnt[base + 3] : 0;
  int tsum = c0 + c1 + c2 + c3;
  s[t] = tsum;
  __syncthreads();
  for (int o = 1; o < 256; o <<= 1) {
    int v = (t >= o) ? s[t - o] : 0;
    __syncthreads();
    s[t] += v;
    __syncthreads();
  }
  int excl = s[t] - tsum;
  if (base + 0 < NN) off[base + 0] = excl;
  if (base + 1 < NN) off[base + 1] = excl + c0;
  if (base + 2 < NN) off[base + 2] = excl + c0 + c1;
  if (base + 3 < NN) off[base + 3] = excl + c0 + c1 + c2;
  if (t == 255) bsum[blockIdx.x] = s[255];
}

__global__ __launch_bounds__(256) void k_scan2(const int* __restrict__ bsum,
    int* __restrict__ bbase) {
  __shared__ int s[256];
  int t = threadIdx.x;
  int v0 = (t < SCAN_BLKS) ? bsum[t] : 0;
  s[t] = v0;
  __syncthreads();
  for (int o = 1; o < 256; o <<= 1) {
    int v = (t >= o) ? s[t - o] : 0;
    __syncthreads();
    s[t] += v;
    __syncthreads();
  }
  if (t < SCAN_BLKS) bbase[t] = s[t] - v0;
}

__global__ __launch_bounds__(256) void k_scan3(int* __restrict__ off,
    const int* __restrict__ bbase, int* __restrict__ nxt) {
  int i = blockIdx.x * 256 + threadIdx.x;
  if (i < NN) {
    int v = off[i] + bbase[i >> 10];
    off[i] = v;
    nxt[i] = v;
  }
  if (i == 0) off[NN] = NE;
}

// ---------- fill CSR records: {row, packed_ea, norm_bits, 0} ----------
__global__ __launch_bounds__(256) void k_fill(const int* __restrict__ ei,
    const int* __restrict__ ea, const float* __restrict__ dis,
    int* __restrict__ nxt, int4* __restrict__ recs) {
  int e = blockIdx.x * 256 + threadIdx.x;
  if (e >= NE) return;
  int r = ei[e], c = ei[NE + e];
  int pa = ea[e * 3 + 0] + ea[e * 3 + 1] * 10 + ea[e * 3 + 2] * 100;
  float nr = dis[r] * dis[c];
  int pos = atomicAdd(&nxt[c], 1);
  recs[pos] = make_int4(r, pa, __float_as_int(nr), 0);
}

// ---------- combined bond table (fp32): btc[pa][d] ----------
__global__ __launch_bounds__(256) void k_btc(const float* __restrict__ bt,
    float* __restrict__ btc) {
  int idx = blockIdx.x * 256 + threadIdx.x;       // 1000*128 exact
  int p = idx >> 7, d = idx & 127;
  int a = p % 10, b = (p / 10) % 10, c = p / 100;
  btc[idx] = bt[(0 * BV + a) * DD + d] + bt[(1 * BV + b) * DD + d]
           + bt[(2 * BV + c) * DD + d];
}

// ---------- W -> bf16 ----------
__global__ __launch_bounds__(256) void k_wconv(const float* __restrict__ W,
    ushort* __restrict__ Wbf) {
  int i = blockIdx.x * 256 + threadIdx.x;         // 5*128*128 exact
  Wbf[i] = f2bf(W[i]);
}

// ---------- MFMA GEMM: hl(fp32) = A' @ Wl^T + bl ----------
// mode0: A' = hbuf (bf16).  mode1: A' = relu(pre*scale+shift) (fp32->bf16), fused out += A'.
// Per block: 128 nodes, 4 waves x 32 nodes. Fragments direct from global (no LDS).
__global__ __launch_bounds__(256) void k_gemm(const ushort* __restrict__ srcbf,
    const float* __restrict__ srcf, const ushort* __restrict__ Wbf,
    const float* __restrict__ bl, const float* __restrict__ scale,
    const float* __restrict__ shift, float* __restrict__ outacc,
    float* __restrict__ hl, int mode) {
  int t = threadIdx.x;
  int lane = t & 63, wave = t >> 6;
  int col = lane & 15, quad = lane >> 4;
  int nb = blockIdx.x * 128 + wave * 32;
  int r0 = nb + col, r1 = nb + 16 + col;
  bool v0 = r0 < NN, v1 = r1 < NN;
  long a0off = (long)(v0 ? r0 : NN - 1) * DD;
  long a1off = (long)(v1 ? r1 : NN - 1) * DD;

  f4v acc[2][8];
#pragma unroll
  for (int i = 0; i < 2; ++i)
#pragma unroll
    for (int j = 0; j < 8; ++j) acc[i][j] = (f4v)0.f;

#pragma unroll 1
  for (int ks = 0; ks < 4; ++ks) {
    int k0 = ks * 32 + quad * 8;                  // A[m=col][k=quad*8+j]
    s8v a0, a1;
    if (mode == 0) {
      a0 = *(const s8v*)&srcbf[a0off + k0];
      a1 = *(const s8v*)&srcbf[a1off + k0];
    } else {
      float4 sc0 = *(const float4*)&scale[k0];
      float4 sc1 = *(const float4*)&scale[k0 + 4];
      float4 sh0 = *(const float4*)&shift[k0];
      float4 sh1 = *(const float4*)&shift[k0 + 4];
      float scv[8] = {sc0.x, sc0.y, sc0.z, sc0.w, sc1.x, sc1.y, sc1.z, sc1.w};
      float shv[8] = {sh0.x, sh0.y, sh0.z, sh0.w, sh1.x, sh1.y, sh1.z, sh1.w};
      float4 p0 = *(const float4*)&srcf[a0off + k0];
      float4 p1 = *(const float4*)&srcf[a0off + k0 + 4];
      float w[8] = {p0.x, p0.y, p0.z, p0.w, p1.x, p1.y, p1.z, p1.w};
#pragma unroll
      for (int j = 0; j < 8; ++j) w[j] = fmaxf(w[j] * scv[j] + shv[j], 0.f);
      if (v0) {
        float4 o0 = *(const float4*)&outacc[a0off + k0];
        float4 o1 = *(const float4*)&outacc[a0off + k0 + 4];
        o0.x += w[0]; o0.y += w[1]; o0.z += w[2]; o0.w += w[3];
        o1.x += w[4]; o1.y += w[5]; o1.z += w[6]; o1.w += w[7];
        *(float4*)&outacc[a0off + k0] = o0;
        *(float4*)&outacc[a0off + k0 + 4] = o1;
      }
#pragma unroll
      for (int j = 0; j < 8; ++j) a0[j] = (short)f2bf(w[j]);
      p0 = *(const float4*)&srcf[a1off + k0];
      p1 = *(const float4*)&srcf[a1off + k0 + 4];
      float u[8] = {p0.x, p0.y, p0.z, p0.w, p1.x, p1.y, p1.z, p1.w};
#pragma unroll
      for (int j = 0; j < 8; ++j) u[j] = fmaxf(u[j] * scv[j] + shv[j], 0.f);
      if (v1) {
        float4 o0 = *(const float4*)&outacc[a1off + k0];
        float4 o1 = *(const float4*)&outacc[a1off + k0 + 4];
        o0.x += u[0]; o0.y += u[1]; o0.z += u[2]; o0.w += u[3];
        o1.x += u[4]; o1.y += u[5]; o1.z += u[6]; o1.w += u[7];
        *(float4*)&outacc[a1off + k0] = o0;
        *(float4*)&outacc[a1off + k0 + 4] = o1;
      }
#pragma unroll
      for (int j = 0; j < 8; ++j) a1[j] = (short)f2bf(u[j]);
    }
#pragma unroll
    for (int j = 0; j < 8; ++j) {                 // B[k][n=col] for out-tile j = W[j*16+col][k]
      s8v bf = *(const s8v*)&Wbf[(j * 16 + col) * DD + k0];
      acc[0][j] = __builtin_amdgcn_mfma_f32_16x16x32_bf16(a0, bf, acc[0][j], 0, 0, 0);
      acc[1][j] = __builtin_amdgcn_mfma_f32_16x16x32_bf16(a1, bf, acc[1][j], 0, 0, 0);
    }
  }

  float bb[8];
#pragma unroll
  for (int j = 0; j < 8; ++j) bb[j] = bl[j * 16 + col];
#pragma unroll
  for (int i = 0; i < 2; ++i) {
    int rowb = nb + i * 16 + quad * 4;            // D: col=lane&15, row=quad*4+reg
#pragma unroll
    for (int r = 0; r < 4; ++r) {
      int n = rowb + r;
      if (n < NN) {
#pragma unroll
        for (int j = 0; j < 8; ++j)
          hl[(long)n * DD + j * 16 + col] = acc[i][j][r] + bb[j];
      }
    }
  }
}

// ---------- gather-aggregate + self term + BN partials ----------
// Half-wave (32 lanes) owns one node; lane covers d = (lane&31)*4 .. +3 (float4,
// 16B/lane = full 512B row per half). Two independent halves per wave -> 2 edges'
// gathers (2x512B) in flight per load instruction (2x MLP vs one-node-per-wave).
__global__ __launch_bounds__(256) void k_aggregate(const float* __restrict__ hl,
    const int* __restrict__ off, const int4* __restrict__ recs,
    const float* __restrict__ btc, const float* __restrict__ rootl,
    const float* __restrict__ invd, float* __restrict__ pre,
    float* __restrict__ gsum, float* __restrict__ gss) {
  __shared__ float4 redS[256], redQ[256];
  int t = threadIdx.x;
  int ql = t & 31;                                 // lane within half-wave
  int hh = t >> 5;                                 // half-slot 0..7
  int d0 = ql * 4;
  int n0 = blockIdx.x * 128;
  float4 rt = *(const float4*)&rootl[d0];
  float4 s = make_float4(0.f, 0.f, 0.f, 0.f);
  float4 q = make_float4(0.f, 0.f, 0.f, 0.f);
#pragma unroll 1
  for (int i = 0; i < 16; ++i) {
    int n = n0 + hh + i * 8;
    if (n >= NN) break;
    int e0 = off[n], e1 = off[n + 1];
    float4 acc = make_float4(0.f, 0.f, 0.f, 0.f);
    for (int e = e0; e < e1; ++e) {
      int4 rc = recs[e];                           // half-uniform broadcast
      float4 hv = *(const float4*)&hl[(long)rc.x * DD + d0];  // 512B/half gather
      float4 ev = *(const float4*)&btc[rc.y * DD + d0];       // L2-resident 512KB
      float nr = __int_as_float(rc.z);
      acc.x += fmaxf(hv.x + ev.x, 0.f) * nr;
      acc.y += fmaxf(hv.y + ev.y, 0.f) * nr;
      acc.z += fmaxf(hv.z + ev.z, 0.f) * nr;
      acc.w += fmaxf(hv.w + ev.w, 0.f) * nr;
    }
    float4 sv = *(const float4*)&hl[(long)n * DD + d0];
    float iv = invd[n];
    float4 p;
    p.x = acc.x + fmaxf(sv.x + rt.x, 0.f) * iv;
    p.y = acc.y + fmaxf(sv.y + rt.y, 0.f) * iv;
    p.z = acc.z + fmaxf(sv.z + rt.z, 0.f) * iv;
    p.w = acc.w + fmaxf(sv.w + rt.w, 0.f) * iv;
    *(float4*)&pre[(long)n * DD + d0] = p;
    s.x += p.x; s.y += p.y; s.z += p.z; s.w += p.w;
    q.x += p.x * p.x; q.y += p.y * p.y; q.z += p.z * p.z; q.w += p.w * p.w;
  }
  redS[t] = s; redQ[t] = q;
  __syncthreads();
  if (t < 128) {
    int d = t, qq = d >> 2, c = d & 3;
    float S = 0.f, Q = 0.f;
#pragma unroll
    for (int h = 0; h < 8; ++h) {
      S += ((const float*)&redS[h * 32 + qq])[c];
      Q += ((const float*)&redQ[h * 32 + qq])[c];
    }
    atomicAdd(&gsum[d], S);
    atomicAdd(&gss[d], Q);
  }
}

__global__ void k_bnfin(const float* __restrict__ gsum, const float* __restrict__ gss,
    const float* __restrict__ gl, const float* __restrict__ bl,
    float* __restrict__ scale, float* __restrict__ shift) {
  int d = threadIdx.x;
  float m = gsum[d] * (1.0f / NN);
  float v = gss[d] * (1.0f / NN) - m * m;
  float sc = gl[d] * rsqrtf(v + EPSV);
  scale[d] = sc;
  shift[d] = bl[d] - m * sc;
}

// ---------- final layer apply (no relu): out += pre*scale + shift ----------
__global__ __launch_bounds__(256) void k_apply_final(const float* __restrict__ pre,
    const float* __restrict__ scale, const float* __restrict__ shift,
    float* __restrict__ out) {
  int idx = blockIdx.x * 256 + threadIdx.x;       // N*D/2 exact
  int dp = idx & 63;
  float2 pv = *(const float2*)&pre[idx * 2];
  float2 o = *(const float2*)&out[idx * 2];
  o.x += pv.x * scale[dp * 2] + shift[dp * 2];
  o.y += pv.y * scale[dp * 2 + 1] + shift[dp * 2 + 1];
  *(float2*)&out[idx * 2] = o;
}

extern "C" void kernel_launch(void* const* d_in, const int* in_sizes, int n_in,
                              void* d_out, int out_size, void* d_ws, size_t ws_size,
                              hipStream_t stream) {
  const int*   x     = (const int*)d_in[0];
  const int*   ei    = (const int*)d_in[1];
  const int*   ea    = (const int*)d_in[2];
  const float* at    = (const float*)d_in[3];
  const float* bt    = (const float*)d_in[4];
  const float* W     = (const float*)d_in[5];
  const float* b     = (const float*)d_in[6];
  const float* root  = (const float*)d_in[7];
  const float* gamma = (const float*)d_in[8];
  const float* beta  = (const float*)d_in[9];
  float* out = (float*)d_out;

  char* ws = (char*)d_ws;
  size_t ND = (size_t)NN * DD;
  float*  hl   = (float*)ws;                        // ND fp32
  float*  pre  = hl + ND;                           // ND fp32
  ushort* hbuf = (ushort*)(pre + ND);               // ND bf16
  int4*   recs = (int4*)(hbuf + ND);                // NE * 16B (offset mult of 16B)
  ushort* Wbf  = (ushort*)(recs + NE);              // 5*128*128 bf16
  float*  btc  = (float*)(Wbf + NL * DD * DD);      // 1000*128 fp32
  float*  deg  = btc + 1000 * DD;                   // N
  float*  dis  = deg + NN;                          // N
  float*  invd = dis + NN;                          // N
  int*    cnt  = (int*)(invd + NN);                 // N
  int*    offa = cnt + NN;                          // N+1 (+3 pad)
  int*    nxt  = offa + NN + 4;                     // N
  int*    bsum = nxt + NN;                          // 256
  int*    bbase= bsum + 256;                        // 256
  float*  gsum = (float*)(bbase + 256);             // D
  float*  gss  = gsum + DD;                         // D
  float*  scaleb = gss + DD;                        // D
  float*  shiftb = scaleb + DD;                     // D

  // ---- precompute ----
  k_deg_init<<<(NN + 255) / 256, 256, 0, stream>>>(deg, cnt);
  k_deg_count<<<(NE + 255) / 256, 256, 0, stream>>>(ei, deg, cnt);
  k_deg_fin<<<(NN + 255) / 256, 256, 0, stream>>>(deg, dis, invd);
  k_scan1<<<SCAN_BLKS, 256, 0, stream>>>(cnt, offa, bsum);
  k_scan2<<<1, 256, 0, stream>>>(bsum, bbase);
  k_scan3<<<(NN + 255) / 256, 256, 0, stream>>>(offa, bbase, nxt);
  k_fill<<<(NE + 255) / 256, 256, 0, stream>>>(ei, ea, dis, nxt, recs);
  k_btc<<<1000 * DD / 256, 256, 0, stream>>>(bt, btc);
  k_wconv<<<NL * DD * DD / 256, 256, 0, stream>>>(W, Wbf);
  k_encode<<<(int)(ND / 2 / 256), 256, 0, stream>>>(x, at, hbuf, out);

  // ---- layers ----
  for (int l = 0; l < NL; ++l) {
    hipMemsetAsync(gsum, 0, 2 * DD * sizeof(float), stream);
    k_gemm<<<(NN + 127) / 128, 256, 0, stream>>>(
        hbuf, pre, Wbf + (size_t)l * DD * DD, b + l * DD,
        scaleb, shiftb, out, hl, (l == 0) ? 0 : 1);
    k_aggregate<<<(NN + 127) / 128, 256, 0, stream>>>(hl, offa, recs, btc,
        root + l * DD, invd, pre, gsum, gss);
    k_bnfin<<<1, DD, 0, stream>>>(gsum, gss, gamma + l * DD, beta + l * DD,
                                  scaleb, shiftb);
  }
  k_apply_final<<<(int)(ND / 2 / 256), 256, 0, stream>>>(pre, scaleb, shiftb, out);
}